// Round 3
// baseline (166.959 us; speedup 1.0000x reference)
//
#include <hip/hip_runtime.h>

// RBF classifier: out = exp(-(||x-c||^2) * exp(-2*log_sigma)) @ W^T + b
// B=16384, D=784, C=2048, OUT=10. All fp32 in/out.
//
// R5: free-run ring schedule. Post-mortem of R3b showed the phase barriers
// serialized the LDS-read window (~2300cy/tile/CU) with the MFMA window
// (~2480cy) -> 32% MfmaUtil. New structure: BK=32, ring-4 LDS (4 x 32KB),
// stage tile t+3 during tile t (3-tile issue->wait distance, ~3600cy),
// ONE counted vmcnt(8) + ONE raw s_barrier per tile, no intra-tile
// barriers: waves free-run within a tile so read/MFMA pipes overlap
// across skewed waves (setprio arbitrates). Epilogue + preps from R3b.

#define B_ROWS 16384
#define D_DIM  784
#define C_DIM  2048
#define NOUT   10
#define KPAD   832
#define NT32   26           // KPAD / 32

typedef __attribute__((ext_vector_type(8))) __bf16 bf16x8;
typedef __attribute__((ext_vector_type(4))) float  f32x4;
typedef __attribute__((ext_vector_type(4))) unsigned short ushort4v;

__device__ __forceinline__ unsigned short f2bf(float f) {
  union { float f; unsigned int u; } v; v.f = f;
  unsigned int u = v.u;
  return (unsigned short)((u + 0x7fffu + ((u >> 16) & 1u)) >> 16);  // RNE
}

// async global->LDS, 16B per lane. LDS dest = wave-uniform base + lane*16.
__device__ __forceinline__ void async16(const unsigned short* g, unsigned short* l) {
  __builtin_amdgcn_global_load_lds((const __attribute__((address_space(1))) void*)g,
                                   (__attribute__((address_space(3))) void*)l,
                                   16, 0, 0);
}

// fp32 row -> bf16 row (padded to KPAD with zeros) + sum of squares.
// one WAVE per row; no LDS, no syncthreads.
__device__ __forceinline__ void conv_row(const float* __restrict__ src,
                                         unsigned short* __restrict__ dst,
                                         float* __restrict__ sq, int row, int lane) {
  const float* s = src + (size_t)row * D_DIM;
  unsigned short* d = dst + (size_t)row * KPAD;
  float acc = 0.f;
#pragma unroll
  for (int c = 0; c < 4; ++c) {
    const int ch = lane + c * 64;           // ushort4 chunk index, 208 total
    if (ch < 196) {
      const float4 v = ((const float4*)s)[ch];
      ushort4v o; o.x = f2bf(v.x); o.y = f2bf(v.y); o.z = f2bf(v.z); o.w = f2bf(v.w);
      *(ushort4v*)(d + ch * 4) = o;
      acc += v.x * v.x + v.y * v.y + v.z * v.z + v.w * v.w;
    } else if (ch < 208) {
      ushort4v z = {0, 0, 0, 0};
      *(ushort4v*)(d + ch * 4) = z;
    }
  }
#pragma unroll
  for (int off = 32; off > 0; off >>= 1) acc += __shfl_down(acc, off);
  if (lane == 0) sq[row] = acc;
}

// one launch for all preprocessing: x rows | centre rows | bias/Wb/scale.
__global__ __launch_bounds__(256) void prep_all(
    const float* __restrict__ x, const float* __restrict__ cen,
    const float* __restrict__ ls, const float* __restrict__ W,
    const float* __restrict__ bias,
    unsigned short* __restrict__ xb, unsigned short* __restrict__ cb,
    unsigned short* __restrict__ wb,
    float* __restrict__ x2, float* __restrict__ c2, float* __restrict__ sc,
    float* __restrict__ out) {
  const int bx = blockIdx.x;
  if (bx < B_ROWS / 4) {
    conv_row(x, xb, x2, bx * 4 + (threadIdx.x >> 6), threadIdx.x & 63);
  } else if (bx < B_ROWS / 4 + C_DIM / 4) {
    conv_row(cen, cb, c2, (bx - B_ROWS / 4) * 4 + (threadIdx.x >> 6), threadIdx.x & 63);
  } else {
    const int i = (bx - (B_ROWS / 4 + C_DIM / 4)) * 256 + threadIdx.x;
    if (i < B_ROWS * NOUT) out[i] = bias[i % NOUT];
    const int j = i - B_ROWS * NOUT;
    if (j >= 0 && j < 16 * C_DIM)
      wb[j] = ((j >> 11) < NOUT) ? f2bf(W[(j >> 11) * C_DIM + (j & 2047)]) : (unsigned short)0;
    const int k = j - 16 * C_DIM;
    if (k >= 0 && k < C_DIM) sc[k] = __expf(-2.f * ls[k]);
  }
}

// --- main fused kernel: 256x256 tile over (B,C), BK=32, 8 waves 2x4
// (wave tile 128x64). LDS: ring of 4 stage buffers (each A 256x32 + B 256x32
// bf16 = 32KB; 128KB total), overlaid in the epilogue by Ph[256][264] bf16
// (132KB); +3KiB f32 vectors on top.
__global__ __launch_bounds__(512, 2) void rbf_main(
    const unsigned short* __restrict__ xb, const unsigned short* __restrict__ cb,
    const unsigned short* __restrict__ wb,
    const float* __restrict__ x2, const float* __restrict__ c2,
    const float* __restrict__ scale, float* __restrict__ out) {
  __shared__ __align__(16) char smem[138240];   // 135168 Ph(>=131072 ring) + 3KB vec
  unsigned short* Ph = (unsigned short*)smem;   // 256 x 264 shorts
  float* x2s = (float*)(smem + 135168);
  float* c2s = (float*)(smem + 136192);
  float* scs = (float*)(smem + 137216);

  const int tid  = threadIdx.x;
  const int w    = tid >> 6;
  const int lane = tid & 63;
  const int q    = lane >> 4;
  const int l16  = lane & 15;
  const int brow = blockIdx.x * 256;
  const int bcol = blockIdx.y * 256;
  const int wr   = (w >> 2) * 128;   // wave row offset: 0 or 128
  const int wc   = (w & 3) * 64;     // wave col offset: 0,64,128,192

  // per-tile vectors (x2 for rows, c2/scale for cols)
  if (tid < 256) { c2s[tid] = c2[bcol + tid]; scs[tid] = scale[bcol + tid]; }
  else           { x2s[tid - 256] = x2[brow + tid - 256]; }
  // drain the preload so the vmcnt FIFO below contains ONLY async16 ops
  asm volatile("s_waitcnt vmcnt(0)" ::: "memory");

  // staging geometry: one issue = 512 thr x 16B = 128 rows x 4 k-octets.
  // thread t covers (row = t>>2, octet = (t&3) ^ (row&3)): XOR swizzle on the
  // GLOBAL source (LDS dest linear, required by global_load_lds), undone on
  // the read side. Per tile: A0(rows 0-127), A1(128-255), B0, B1 = 4 issues.
  const int srow = tid >> 2;                      // 0..127
  const int soct = (tid & 3) ^ (srow & 3);        // swizzled source octet
  const unsigned short* sA = xb + (size_t)(brow + srow) * KPAD + soct * 8;
  const unsigned short* sB = cb + (size_t)(bcol + srow) * KPAD + soct * 8;
  const int wslot = w * 512;                      // shorts; +lane*8 implicit

#define STG(T) { unsigned short* bb = (unsigned short*)(smem + ((T) & 3) * 32768); \
    const int k0_ = (T) * 32;                                                      \
    async16(sA + k0_,              bb         + wslot);                            \
    async16(sA + 128*KPAD + k0_,   bb + 4096  + wslot);                            \
    async16(sB + k0_,              bb + 8192  + wslot);                            \
    async16(sB + 128*KPAD + k0_,   bb + 12288 + wslot); }

  // prologue: stage tiles 0,1,2 (12 issues in flight)
  STG(0); STG(1); STG(2);

  f32x4 acc[8][4] = {};
  const int osw = (q ^ (l16 & 3)) << 3;   // read-side octet deswizzle, shorts

  for (int t = 0; t < NT32; ++t) {
    // entry: retire tile t's 4 issues, keep t+1/t+2 (8) in flight
    if (t < NT32 - 2)       asm volatile("s_waitcnt vmcnt(8)" ::: "memory");
    else if (t == NT32 - 2) asm volatile("s_waitcnt vmcnt(4)" ::: "memory");
    else                    asm volatile("s_waitcnt vmcnt(0)" ::: "memory");
    __builtin_amdgcn_s_barrier();   // raw: counted loads stay in flight

    if (t < NT32 - 3) STG(t + 3);   // writes buf[(t-1)&3]: reads done pre-barrier

    const unsigned short* As = (const unsigned short*)(smem + (t & 3) * 32768);
    const unsigned short* Bs = As + 8192;
    bf16x8 af[8], bfr[4];
#pragma unroll
    for (int i = 0; i < 8; ++i)
      af[i] = *(const bf16x8*)&As[(wr + i * 16 + l16) * 32 + osw];
#pragma unroll
    for (int j = 0; j < 4; ++j)
      bfr[j] = *(const bf16x8*)&Bs[(wc + j * 16 + l16) * 32 + osw];
    __builtin_amdgcn_s_setprio(1);
#pragma unroll
    for (int i = 0; i < 8; ++i)
#pragma unroll
      for (int j = 0; j < 4; ++j)
        acc[i][j] = __builtin_amdgcn_mfma_f32_16x16x32_bf16(af[i], bfr[j], acc[i][j], 0, 0, 0);
    __builtin_amdgcn_s_setprio(0);
  }
#undef STG

  __syncthreads();   // drain everything; Ph overlays the ring buffers

  // epilogue 1: d2 -> phi -> Ph (bf16). C/D layout: col=lane&15, row=q*4+r.
#pragma unroll
  for (int i = 0; i < 8; ++i) {
#pragma unroll
    for (int j = 0; j < 4; ++j) {
      const int cl = wc + j * 16 + l16;
      const float c2v = c2s[cl];
      const float sc = scs[cl];
#pragma unroll
      for (int r = 0; r < 4; ++r) {
        const int rl = wr + i * 16 + q * 4 + r;
        float d2 = fmaxf(x2s[rl] + c2v - 2.f * acc[i][j][r], 0.f);
        Ph[rl * 264 + cl] = f2bf(__expf(-d2 * sc));
      }
    }
  }
  __syncthreads();

  // epilogue 2: out_tile(256x10) = Ph(256x256) @ Wb(16-row slice)^T, K=256.
  // wave w handles rows w*32 .. w*32+31 (2 M-frags).
  f32x4 oacc[2] = {};
#pragma unroll
  for (int kk = 0; kk < 8; ++kk) {
    const bf16x8 bw = *(const bf16x8*)&wb[(size_t)l16 * C_DIM + bcol + kk * 32 + q * 8];
#pragma unroll
    for (int mi = 0; mi < 2; ++mi) {
      const bf16x8 ap = *(const bf16x8*)&Ph[(w * 32 + mi * 16 + l16) * 264 + kk * 32 + q * 8];
      oacc[mi] = __builtin_amdgcn_mfma_f32_16x16x32_bf16(ap, bw, oacc[mi], 0, 0, 0);
    }
  }
  if (l16 < NOUT) {
#pragma unroll
    for (int mi = 0; mi < 2; ++mi)
#pragma unroll
      for (int r = 0; r < 4; ++r) {
        const int grow = brow + w * 32 + mi * 16 + q * 4 + r;
        atomicAdd(&out[grow * NOUT + l16], oacc[mi][r]);
      }
  }
}

extern "C" void kernel_launch(void* const* d_in, const int* in_sizes, int n_in,
                              void* d_out, int out_size, void* d_ws, size_t ws_size,
                              hipStream_t stream) {
  const float* x    = (const float*)d_in[0];  // (16384,784)
  const float* cen  = (const float*)d_in[1];  // (2048,784)
  const float* ls   = (const float*)d_in[2];  // (2048,)
  const float* W    = (const float*)d_in[3];  // (10,2048)
  const float* bias = (const float*)d_in[4];  // (10,)
  float* out = (float*)d_out;                 // (16384,10)

  unsigned char* ws = (unsigned char*)d_ws;
  unsigned short* xb  = (unsigned short*)(ws);              // 16384*832*2 = 27,262,976
  unsigned short* cbf = (unsigned short*)(ws + 27262976);   //  2048*832*2 =  3,407,872
  unsigned short* wb  = (unsigned short*)(ws + 30670848);   //   16*2048*2 =     65,536
  float* x2 = (float*)(ws + 30736384);                      // 16384*4
  float* c2 = (float*)(ws + 30801920);                      //  2048*4
  float* sc = (float*)(ws + 30810112);                      //  2048*4   (end 30,818,304)

  const int prep_blocks = B_ROWS / 4 + C_DIM / 4 +
                          (B_ROWS * NOUT + 16 * C_DIM + C_DIM + 255) / 256;
  prep_all<<<prep_blocks, 256, 0, stream>>>(x, cen, ls, W, bias, xb, cbf, wb, x2, c2, sc, out);
  rbf_main<<<dim3(B_ROWS / 256, C_DIM / 256), 512, 0, stream>>>(xb, cbf, wb, x2, c2, sc, out);
}

// Round 5
// 160.619 us; speedup vs baseline: 1.0395x; 1.0395x over previous
//
#include <hip/hip_runtime.h>

// RBF classifier: out = exp(-(||x-c||^2) * exp(-2*log_sigma)) @ W^T + b
// B=16384, D=784, C=2048, OUT=10. All fp32 in/out.
//
// R6b: byte-identical resubmit of R6 (container-level infra failure, same
// signature as R3 which passed unchanged as R3b; audit found no hang
// mechanism and the structurally-identical free-run R5 executed fine).
// R6 = free-run ring-2 with the PROVEN BK=64 layout (128B rows, XOR over 8
// octets -> 2 lanes/bank, conflict-free). Per K-tile: ONE vmcnt wait
// (issued a full tile earlier, ~free) + ONE raw s_barrier; STG(t+1) right
// after the barrier; then all ds_reads then all MFMAs -- waves skew within
// the tile so the LDS pipe and MFMA pipe overlap across waves.

#define B_ROWS 16384
#define D_DIM  784
#define C_DIM  2048
#define NOUT   10
#define KPAD   832
#define BK     64
#define NT     13            // KPAD / BK

typedef __attribute__((ext_vector_type(8))) __bf16 bf16x8;
typedef __attribute__((ext_vector_type(4))) float  f32x4;
typedef __attribute__((ext_vector_type(4))) unsigned short ushort4v;

__device__ __forceinline__ unsigned short f2bf(float f) {
  union { float f; unsigned int u; } v; v.f = f;
  unsigned int u = v.u;
  return (unsigned short)((u + 0x7fffu + ((u >> 16) & 1u)) >> 16);  // RNE
}

// async global->LDS, 16B per lane. LDS dest = wave-uniform base + lane*16.
__device__ __forceinline__ void async16(const unsigned short* g, unsigned short* l) {
  __builtin_amdgcn_global_load_lds((const __attribute__((address_space(1))) void*)g,
                                   (__attribute__((address_space(3))) void*)l,
                                   16, 0, 0);
}

// fp32 row -> bf16 row (padded to KPAD with zeros) + sum of squares.
// one WAVE per row; no LDS, no syncthreads.
__device__ __forceinline__ void conv_row(const float* __restrict__ src,
                                         unsigned short* __restrict__ dst,
                                         float* __restrict__ sq, int row, int lane) {
  const float* s = src + (size_t)row * D_DIM;
  unsigned short* d = dst + (size_t)row * KPAD;
  float acc = 0.f;
#pragma unroll
  for (int c = 0; c < 4; ++c) {
    const int ch = lane + c * 64;           // ushort4 chunk index, 208 total
    if (ch < 196) {
      const float4 v = ((const float4*)s)[ch];
      ushort4v o; o.x = f2bf(v.x); o.y = f2bf(v.y); o.z = f2bf(v.z); o.w = f2bf(v.w);
      *(ushort4v*)(d + ch * 4) = o;
      acc += v.x * v.x + v.y * v.y + v.z * v.z + v.w * v.w;
    } else if (ch < 208) {
      ushort4v z = {0, 0, 0, 0};
      *(ushort4v*)(d + ch * 4) = z;
    }
  }
#pragma unroll
  for (int off = 32; off > 0; off >>= 1) acc += __shfl_down(acc, off);
  if (lane == 0) sq[row] = acc;
}

// one launch for all preprocessing: x rows | centre rows | bias/Wb/scale.
__global__ __launch_bounds__(256) void prep_all(
    const float* __restrict__ x, const float* __restrict__ cen,
    const float* __restrict__ ls, const float* __restrict__ W,
    const float* __restrict__ bias,
    unsigned short* __restrict__ xb, unsigned short* __restrict__ cb,
    unsigned short* __restrict__ wb,
    float* __restrict__ x2, float* __restrict__ c2, float* __restrict__ sc,
    float* __restrict__ out) {
  const int bx = blockIdx.x;
  if (bx < B_ROWS / 4) {
    conv_row(x, xb, x2, bx * 4 + (threadIdx.x >> 6), threadIdx.x & 63);
  } else if (bx < B_ROWS / 4 + C_DIM / 4) {
    conv_row(cen, cb, c2, (bx - B_ROWS / 4) * 4 + (threadIdx.x >> 6), threadIdx.x & 63);
  } else {
    const int i = (bx - (B_ROWS / 4 + C_DIM / 4)) * 256 + threadIdx.x;
    if (i < B_ROWS * NOUT) out[i] = bias[i % NOUT];
    const int j = i - B_ROWS * NOUT;
    if (j >= 0 && j < 16 * C_DIM)
      wb[j] = ((j >> 11) < NOUT) ? f2bf(W[(j >> 11) * C_DIM + (j & 2047)]) : (unsigned short)0;
    const int k = j - 16 * C_DIM;
    if (k >= 0 && k < C_DIM) sc[k] = __expf(-2.f * ls[k]);
  }
}

// --- main fused kernel: 256x256 tile over (B,C), BK=64, 8 waves 2x4
// (wave tile 128x64). LDS: ring-2 stage buffers (each A 256x64 + B 256x64
// bf16 = 64KB; 128KB total), overlaid in the epilogue by Ph[256][264] bf16
// (132KB); +3KiB f32 vectors on top.
__global__ __launch_bounds__(512, 2) void rbf_main(
    const unsigned short* __restrict__ xb, const unsigned short* __restrict__ cb,
    const unsigned short* __restrict__ wb,
    const float* __restrict__ x2, const float* __restrict__ c2,
    const float* __restrict__ scale, float* __restrict__ out) {
  __shared__ __align__(16) char smem[138240];   // 135168 Ph (>=131072 ring) + 3KB vec
  unsigned short* Ph = (unsigned short*)smem;   // 256 x 264 shorts
  float* x2s = (float*)(smem + 135168);
  float* c2s = (float*)(smem + 136192);
  float* scs = (float*)(smem + 137216);

  const int tid  = threadIdx.x;
  const int w    = tid >> 6;
  const int lane = tid & 63;
  const int q    = lane >> 4;
  const int l16  = lane & 15;
  const int swz  = l16 & 7;
  const int brow = blockIdx.x * 256;
  const int bcol = blockIdx.y * 256;
  const int wr   = (w >> 2) * 128;   // wave row offset: 0 or 128
  const int wc   = (w & 3) * 64;     // wave col offset: 0,64,128,192

  // per-tile vectors (x2 for rows, c2/scale for cols)
  if (tid < 256) { c2s[tid] = c2[bcol + tid]; scs[tid] = scale[bcol + tid]; }
  else           { x2s[tid - 256] = x2[brow + tid - 256]; }
  // drain the preload so the vmcnt FIFO below contains ONLY async16 ops
  asm volatile("s_waitcnt vmcnt(0)" ::: "memory");

  // staging: thread t covers (row = r*64 + t/8, k-octet (t&7) ^ (row&7)) per
  // issue r (8KB each; A tile = 4 issues, B tile = 4 issues). XOR swizzle on
  // the GLOBAL source (LDS dest linear, required by global_load_lds), undone
  // on the read side. Row = 64 shorts = 128B = all 32 banks: conflict-free.
  const int srow = tid >> 3;                       // 0..63
  const int skc  = (tid & 7) ^ (srow & 7);
  const unsigned short* gA = xb + (size_t)(brow + srow) * KPAD + skc * 8;
  const unsigned short* gB = cb + (size_t)(bcol + srow) * KPAD + skc * 8;
  const int ldst = w * 512;                        // shorts; +lane*8 implicit

  // one STG = full K-tile (A 4 issues + B 4 issues = 64KB into buf[T&1])
#define STG(T) { unsigned short* bbA = (unsigned short*)(smem + ((T) & 1) * 65536);   \
    unsigned short* bbB = bbA + 16384;                                                \
    const int k0_ = (T) * BK;                                                         \
    async16(gA + k0_,                bbA         + ldst);                             \
    async16(gA + (size_t)64*KPAD  + k0_, bbA + 4096  + ldst);                         \
    async16(gA + (size_t)128*KPAD + k0_, bbA + 8192  + ldst);                         \
    async16(gA + (size_t)192*KPAD + k0_, bbA + 12288 + ldst);                         \
    async16(gB + k0_,                bbB         + ldst);                             \
    async16(gB + (size_t)64*KPAD  + k0_, bbB + 4096  + ldst);                         \
    async16(gB + (size_t)128*KPAD + k0_, bbB + 8192  + ldst);                         \
    async16(gB + (size_t)192*KPAD + k0_, bbB + 12288 + ldst); }

  // prologue: stage tiles 0 and 1 (16 issues in flight)
  STG(0); STG(1);

  f32x4 acc[8][4] = {};

  for (int t = 0; t < NT; ++t) {
    // entry: tile t must have landed. t=0: keep tile 1's 8 in flight.
    // t>=1: the 8 outstanding are tile t's own, issued a full tile (~2600cy)
    // ago -> this wait is effectively free (unlike a short-distance drain).
    if (t == 0) asm volatile("s_waitcnt vmcnt(8)" ::: "memory");
    else        asm volatile("s_waitcnt vmcnt(0)" ::: "memory");
    __builtin_amdgcn_s_barrier();   // raw: in-flight counted loads survive

    // stage t+1 into buf[(t+1)&1]: every wave passing the barrier has
    // register-consumed its reads of that buffer (tile t-1) -> WAR-safe.
    if (t >= 1 && t < NT - 1) STG(t + 1);

    const unsigned short* As = (const unsigned short*)(smem + (t & 1) * 65536);
    const unsigned short* Bs = As + 16384;
    bf16x8 af0[4], af1[4], bfr[4];
#pragma unroll
    for (int ks = 0; ks < 2; ++ks) {
#pragma unroll
      for (int j = 0; j < 4; ++j)
        bfr[j] = *(const bf16x8*)&Bs[(wc + j * 16 + l16) * 64 + (((ks * 4 + q) ^ swz) << 3)];
#pragma unroll
      for (int ii = 0; ii < 4; ++ii)
        af0[ii] = *(const bf16x8*)&As[(wr + ii * 16 + l16) * 64 + (((ks * 4 + q) ^ swz) << 3)];
#pragma unroll
      for (int ii = 0; ii < 4; ++ii)
        af1[ii] = *(const bf16x8*)&As[(wr + 64 + ii * 16 + l16) * 64 + (((ks * 4 + q) ^ swz) << 3)];
      __builtin_amdgcn_s_setprio(1);
#pragma unroll
      for (int ii = 0; ii < 4; ++ii)
#pragma unroll
        for (int j = 0; j < 4; ++j)
          acc[ii][j] = __builtin_amdgcn_mfma_f32_16x16x32_bf16(af0[ii], bfr[j], acc[ii][j], 0, 0, 0);
#pragma unroll
      for (int ii = 0; ii < 4; ++ii)
#pragma unroll
        for (int j = 0; j < 4; ++j)
          acc[4 + ii][j] = __builtin_amdgcn_mfma_f32_16x16x32_bf16(af1[ii], bfr[j], acc[4 + ii][j], 0, 0, 0);
      __builtin_amdgcn_s_setprio(0);
    }
  }
#undef STG

  __syncthreads();   // full drain; Ph overlays the ring buffers

  // epilogue 1: d2 -> phi -> Ph (bf16). C/D layout: col=lane&15, row=q*4+r.
#pragma unroll
  for (int i = 0; i < 8; ++i) {
#pragma unroll
    for (int j = 0; j < 4; ++j) {
      const int cl = wc + j * 16 + l16;
      const float c2v = c2s[cl];
      const float sc = scs[cl];
#pragma unroll
      for (int r = 0; r < 4; ++r) {
        const int rl = wr + i * 16 + q * 4 + r;
        float d2 = fmaxf(x2s[rl] + c2v - 2.f * acc[i][j][r], 0.f);
        Ph[rl * 264 + cl] = f2bf(__expf(-d2 * sc));
      }
    }
  }
  __syncthreads();

  // epilogue 2: out_tile(256x10) = Ph(256x256) @ Wb(16-row slice)^T, K=256.
  // wave w handles rows w*32 .. w*32+31 (2 M-frags).
  f32x4 oacc[2] = {};
#pragma unroll
  for (int kk = 0; kk < 8; ++kk) {
    const bf16x8 bw = *(const bf16x8*)&wb[(size_t)l16 * C_DIM + bcol + kk * 32 + q * 8];
#pragma unroll
    for (int mi = 0; mi < 2; ++mi) {
      const bf16x8 ap = *(const bf16x8*)&Ph[(w * 32 + mi * 16 + l16) * 264 + kk * 32 + q * 8];
      oacc[mi] = __builtin_amdgcn_mfma_f32_16x16x32_bf16(ap, bw, oacc[mi], 0, 0, 0);
    }
  }
  if (l16 < NOUT) {
#pragma unroll
    for (int mi = 0; mi < 2; ++mi)
#pragma unroll
      for (int r = 0; r < 4; ++r) {
        const int grow = brow + w * 32 + mi * 16 + q * 4 + r;
        atomicAdd(&out[grow * NOUT + l16], oacc[mi][r]);
      }
  }
}

extern "C" void kernel_launch(void* const* d_in, const int* in_sizes, int n_in,
                              void* d_out, int out_size, void* d_ws, size_t ws_size,
                              hipStream_t stream) {
  const float* x    = (const float*)d_in[0];  // (16384,784)
  const float* cen  = (const float*)d_in[1];  // (2048,784)
  const float* ls   = (const float*)d_in[2];  // (2048,)
  const float* W    = (const float*)d_in[3];  // (10,2048)
  const float* bias = (const float*)d_in[4];  // (10,)
  float* out = (float*)d_out;                 // (16384,10)

  unsigned char* ws = (unsigned char*)d_ws;
  unsigned short* xb  = (unsigned short*)(ws);              // 16384*832*2 = 27,262,976
  unsigned short* cbf = (unsigned short*)(ws + 27262976);   //  2048*832*2 =  3,407,872
  unsigned short* wb  = (unsigned short*)(ws + 30670848);   //   16*2048*2 =     65,536
  float* x2 = (float*)(ws + 30736384);                      // 16384*4
  float* c2 = (float*)(ws + 30801920);                      //  2048*4
  float* sc = (float*)(ws + 30810112);                      //  2048*4   (end 30,818,304)

  const int prep_blocks = B_ROWS / 4 + C_DIM / 4 +
                          (B_ROWS * NOUT + 16 * C_DIM + C_DIM + 255) / 256;
  prep_all<<<prep_blocks, 256, 0, stream>>>(x, cen, ls, W, bias, xb, cbf, wb, x2, c2, sc, out);
  rbf_main<<<dim3(B_ROWS / 256, C_DIM / 256), 512, 0, stream>>>(xb, cbf, wb, x2, c2, sc, out);
}